// Round 4
// baseline (48146.481 us; speedup 1.0000x reference)
//
#include <hip/hip_runtime.h>

#define NPTS 8192
#define N2 (NPTS * 2)
#define TPB 512            // main kernels: 512 threads
#define NBLK 256           // 1 block per CU
#define IPB 32             // i-rows owned per block
#define NSLICE 16          // j-slices (TPB / IPB)
#define JCH 1024           // j chunk staged in LDS
#define NJCH (NPTS / JCH)  // 8 chunks
#define JPT (JCH / NSLICE) // 64 inner iterations per chunk
#define T_ITERS 1408
#define NUG 1.0e-4
#define LAM 1.0e-5

typedef double2 dbl2;

// ---------------- setup: pack scaled points + norms, init CG state ----------------
// u = x/sqrt(2) => K_ij = exp(-(|u_i|^2 + |u_j|^2 - 2 u_i.u_j))
// Writes r_{-1}=z, p_{-1}=0, q_{-1}=0 into slot 1; x=0; rho_0 partials.
extern "C" __global__ void __launch_bounds__(TPB)
k_setup(const float* __restrict__ Xmu, const float* __restrict__ Yeta,
        const float* __restrict__ Ymu, const float* __restrict__ Z,
        float* __restrict__ U4, float* __restrict__ UN,
        float* __restrict__ M4, float* __restrict__ Y4,
        double* __restrict__ x, double* __restrict__ r1,
        double* __restrict__ p1, double* __restrict__ q1,
        double* __restrict__ rrsetup)
{
  const float c = 0.70710678118654752f;
  int tid = threadIdx.x;
  int idx = blockIdx.x * TPB + tid;          // 0..16383
  int i = idx >> 1;
  float z = Z[idx];
  r1[idx] = (double)z;
  p1[idx] = 0.0;
  q1[idx] = 0.0;
  x[idx] = 0.0;
  if ((idx & 1) == 0) {
    float a0 = Xmu[2 * i], a1 = Xmu[2 * i + 1];
    float e0 = Yeta[2 * i], e1 = Yeta[2 * i + 1];
    float m0 = Ymu[2 * i], m1 = Ymu[2 * i + 1];
    float z0 = Z[2 * i], z1 = Z[2 * i + 1];
    float u0 = c * a0, u1 = c * a1, u2 = c * e0, u3 = c * e1;
    ((float4*)U4)[i] = make_float4(u0, u1, u2, u3);
    UN[i] = fmaf(u3, u3, fmaf(u2, u2, fmaf(u1, u1, u0 * u0)));
    ((float4*)M4)[i] = make_float4(a0, a1, e0 + z0, e1 + z1);
    ((float4*)Y4)[i] = make_float4(a0, a1, m0, m1);
  }
  // rho_0 = <z,z> per column (parity-preserving reduce 512 -> 2)
  __shared__ double sd[TPB];
  sd[tid] = (double)z * (double)z;
  __syncthreads();
  for (int st = TPB >> 1; st >= 2; st >>= 1) {
    if (tid < st) sd[tid] += sd[tid + st];
    __syncthreads();
  }
  if (tid < 2) rrsetup[blockIdx.x * 2 + tid] = sd[tid];
}

// ---------------- MMD: three fused Gram sums (256 threads/block) ----------------
#define MTPB 256
#define MCH 1024
extern "C" __global__ void __launch_bounds__(MTPB)
k_mmd(const float* __restrict__ M4, const float* __restrict__ Y4,
      double* __restrict__ mmdpart)
{
  __shared__ float4 sM[MCH];
  __shared__ float4 sY[MCH];
  __shared__ double sred[MTPB];
  int tid = threadIdx.x;
  int blk = blockIdx.x;            // 256 = 32 itiles x 8 chunks
  int itile = blk >> 3;
  int ch = blk & 7;
  int j0 = ch * MCH;
  for (int u = tid; u < MCH; u += MTPB) {
    sM[u] = ((const float4*)M4)[j0 + u];
    sY[u] = ((const float4*)Y4)[j0 + u];
  }
  __syncthreads();
  int i = itile * MTPB + tid;
  float4 mi = ((const float4*)M4)[i];
  float4 yi = ((const float4*)Y4)[i];
  double szz = 0.0, szy = 0.0, syy = 0.0;
  for (int jj = 0; jj < MCH; ++jj) {
    float4 mj = sM[jj];
    float4 yj = sY[jj];
    float d0 = mi.x - mj.x, d1 = mi.y - mj.y;     // shared X_mu part
    float a = fmaf(d1, d1, d0 * d0);
    float u0 = mi.z - mj.z, u1 = mi.w - mj.w;
    float v0 = mi.z - yj.z, v1 = mi.w - yj.w;
    float w0 = yi.z - yj.z, w1 = yi.w - yj.w;
    float dzz = fmaf(u0, u0, fmaf(u1, u1, a));
    float dzy = fmaf(v0, v0, fmaf(v1, v1, a));
    float dyy = fmaf(w0, w0, fmaf(w1, w1, a));
    szz += (double)__expf(-0.5f * dzz);
    szy += (double)__expf(-0.5f * dzy);
    syy += (double)__expf(-0.5f * dyy);
  }
  double v[3] = {szz, szy, syy};
  for (int k = 0; k < 3; ++k) {
    sred[tid] = v[k];
    __syncthreads();
    for (int st = MTPB >> 1; st >= 1; st >>= 1) {
      if (tid < st) sred[tid] += sred[tid + st];
      __syncthreads();
    }
    if (tid == 0) mmdpart[blk * 3 + k] = sred[0];
    __syncthreads();
  }
}

// ---------------- fused CG iteration: one kernel = one full CG step ----------------
// Block owns IPB=32 i-rows; sweeps all j via LDS chunks.
// Scalars: alpha_{t-1} = rho_{t-1}/pq_{t-1};
//          rho_t = rho_{t-1} - 2 a rq_{t-1} + a^2 qq_{t-1}; beta_t = rho_t/rho_{t-1}.
// Staging recomputes p_t on the fly: pn = beta*p_{t-1} + (r_{t-1} - alpha*q_{t-1}).
// Epilogue (owned i): write r_t, p_t, q_t (ping-pong slots), x_t; partials pq/rq/qq.
extern "C" __global__ void __launch_bounds__(TPB)
k_cg(const float* __restrict__ U4, const float* __restrict__ UN,
     const double* __restrict__ rprev, const double* __restrict__ pprev,
     const double* __restrict__ qprev,
     double* __restrict__ rnext, double* __restrict__ pnext,
     double* __restrict__ qnext, double* __restrict__ x,
     const double* __restrict__ part_prev,  // [3*512]: pq | rq | qq
     double* __restrict__ part_next,
     const double* __restrict__ rho_prev,   // [2]
     double* __restrict__ rho_next,         // [2]
     const double* __restrict__ rrsetup,    // [64], t==0 only
     int t)
{
  __shared__ float4 sw[JCH];                 // 2*u_j
  __shared__ float4 sa[JCH];                 // (n_j, pn0_j, pn1_j, 0)
  __shared__ float qred[NSLICE][IPB][2];
  __shared__ double s1[TPB], s2[TPB], s3[TPB];
  __shared__ double sc[4];                   // a0, a1, b0, b1

  int tid = threadIdx.x;
  int blk = blockIdx.x;

  // ---- scalar phase ----
  if (t == 0) {
    s1[tid] = (tid < 64) ? rrsetup[tid] : 0.0;
    __syncthreads();
    for (int st = 32; st >= 2; st >>= 1) {
      if (tid < st) s1[tid] += s1[tid + st];
      __syncthreads();
    }
    if (tid < 2) {
      rho_next[tid] = s1[tid];               // rho_0 (identical dup-write per block)
      sc[tid] = 0.0;                          // alpha = 0
      sc[2 + tid] = 0.0;                      // beta = 0
    }
    __syncthreads();
  } else {
    s1[tid] = part_prev[tid];
    s2[tid] = part_prev[512 + tid];
    s3[tid] = part_prev[1024 + tid];
    __syncthreads();
    for (int st = 256; st >= 2; st >>= 1) {
      if (tid < st) {
        s1[tid] += s1[tid + st];
        s2[tid] += s2[tid + st];
        s3[tid] += s3[tid + st];
      }
      __syncthreads();
    }
    if (tid < 2) {
      double rho_o = rho_prev[tid];
      double al = rho_o / s1[tid];
      double rho_n = fma(al, fma(al, s3[tid], -2.0 * s2[tid]), rho_o);
      rho_next[tid] = rho_n;                 // identical dup-write per block
      sc[tid] = al;
      sc[2 + tid] = rho_n / rho_o;           // beta
    }
    __syncthreads();
  }
  double a0 = sc[0], a1 = sc[1], b0 = sc[2], b1 = sc[3];

  // ---- matvec: q_i = sum_j K_ij * p_j (f32), all j ----
  int il = tid & (IPB - 1);
  int slice = tid >> 5;
  int irow = blk * IPB + il;
  float4 ui = ((const float4*)U4)[irow];
  float ni = UN[irow];
  float qacc0 = 0.f, qacc1 = 0.f;
  for (int c = 0; c < NJCH; ++c) {
    int jb = c * JCH;
    for (int u = tid; u < JCH; u += TPB) {   // 2 iterations
      int j = jb + u;
      float4 uj = ((const float4*)U4)[j];
      dbl2 rj = ((const dbl2*)rprev)[j];
      dbl2 pj = ((const dbl2*)pprev)[j];
      dbl2 qj = ((const dbl2*)qprev)[j];
      double pn0 = fma(b0, pj.x, fma(-a0, qj.x, rj.x));
      double pn1 = fma(b1, pj.y, fma(-a1, qj.y, rj.y));
      sw[u] = make_float4(2.f * uj.x, 2.f * uj.y, 2.f * uj.z, 2.f * uj.w);
      sa[u] = make_float4(UN[j], (float)pn0, (float)pn1, 0.f);
    }
    __syncthreads();
    int jlo = slice * JPT;
#pragma unroll 4
    for (int jj = 0; jj < JPT; ++jj) {
      float4 w = sw[jlo + jj];
      float4 aa = sa[jlo + jj];
      float tt = ni + aa.x;
      tt = fmaf(-ui.x, w.x, tt);
      tt = fmaf(-ui.y, w.y, tt);
      tt = fmaf(-ui.z, w.z, tt);
      tt = fmaf(-ui.w, w.w, tt);
      float e = __expf(-tt);
      qacc0 = fmaf(e, aa.y, qacc0);
      qacc1 = fmaf(e, aa.z, qacc1);
    }
    __syncthreads();
  }
  qred[slice][il][0] = qacc0;
  qred[slice][il][1] = qacc1;
  __syncthreads();

  // ---- epilogue: owned-row state update + partials ----
  double pqv = 0.0, rqv = 0.0, qqv = 0.0;
  if (tid < 64) {
    int il2 = tid >> 1, col = tid & 1;
    int idx = ((blk * IPB + il2) << 1) | col;
    double qg = 0.0;
#pragma unroll
    for (int s = 0; s < NSLICE; ++s) qg += (double)qred[s][il2][col];
    double al = col ? a1 : a0;
    double be = col ? b1 : b0;
    double rold = rprev[idx], pold = pprev[idx], qold = qprev[idx];
    double rn = fma(-al, qold, rold);        // r_t
    double pn = fma(be, pold, rn);           // p_t
    double xn = fma(al, pold, x[idx]);       // x_t
    double qn = fma((double)NUG, pn, qg);    // q_t = G p_t + eta p_t
    rnext[idx] = rn;
    pnext[idx] = pn;
    qnext[idx] = qn;
    x[idx] = xn;
    pqv = pn * qn;
    rqv = rn * qn;
    qqv = qn * qn;
  }
  s1[tid] = pqv; s2[tid] = rqv; s3[tid] = qqv;
  __syncthreads();
  for (int st = 32; st >= 2; st >>= 1) {
    if (tid < st) {
      s1[tid] += s1[tid + st];
      s2[tid] += s2[tid + st];
      s3[tid] += s3[tid + st];
    }
    __syncthreads();
  }
  if (tid < 2) {
    part_next[blk * 2 + tid] = s1[tid];
    part_next[512 + blk * 2 + tid] = s2[tid];
    part_next[1024 + blk * 2 + tid] = s3[tid];
  }
}

// ---------------- final: last x half-step + combine ----------------
extern "C" __global__ void __launch_bounds__(TPB)
k_final(const float* __restrict__ Z, const double* __restrict__ x,
        const double* __restrict__ plast, const double* __restrict__ part_last,
        const double* __restrict__ rho_last, const double* __restrict__ mmdpart,
        float* __restrict__ out)
{
  __shared__ double s1[TPB];
  __shared__ double sc2[2];
  int tid = threadIdx.x;
  // alpha_{T-1} = rho_{T-1} / pq_{T-1}
  s1[tid] = part_last[tid];
  __syncthreads();
  for (int st = 256; st >= 2; st >>= 1) {
    if (tid < st) s1[tid] += s1[tid + st];
    __syncthreads();
  }
  if (tid < 2) sc2[tid] = rho_last[tid] / s1[tid];
  __syncthreads();
  double al = sc2[tid & 1];
  double zx = 0.0;
  for (int idx = tid; idx < N2; idx += TPB)  // stride even -> col parity fixed
    zx += (double)Z[idx] * fma(al, plast[idx], x[idx]);
  // full reduces: zx, then three mmd sums
  double ZX, S0, S1v, S2v;
  s1[tid] = zx;
  __syncthreads();
  for (int st = 256; st >= 1; st >>= 1) { if (tid < st) s1[tid] += s1[tid + st]; __syncthreads(); }
  ZX = s1[0]; __syncthreads();
  s1[tid] = (tid < 256) ? mmdpart[tid * 3 + 0] : 0.0;
  __syncthreads();
  for (int st = 256; st >= 1; st >>= 1) { if (tid < st) s1[tid] += s1[tid + st]; __syncthreads(); }
  S0 = s1[0]; __syncthreads();
  s1[tid] = (tid < 256) ? mmdpart[tid * 3 + 1] : 0.0;
  __syncthreads();
  for (int st = 256; st >= 1; st >>= 1) { if (tid < st) s1[tid] += s1[tid + st]; __syncthreads(); }
  S1v = s1[0]; __syncthreads();
  s1[tid] = (tid < 256) ? mmdpart[tid * 3 + 2] : 0.0;
  __syncthreads();
  for (int st = 256; st >= 1; st >>= 1) { if (tid < st) s1[tid] += s1[tid + st]; __syncthreads(); }
  S2v = s1[0];
  if (tid == 0) {
    double nn = (double)NPTS * (double)NPTS;
    double mmd = (S0 - 2.0 * S1v + S2v) / nn;
    out[0] = (float)(mmd + LAM * ZX);
  }
}

extern "C" void kernel_launch(void* const* d_in, const int* in_sizes, int n_in,
                              void* d_out, int out_size, void* d_ws, size_t ws_size,
                              hipStream_t stream)
{
  (void)in_sizes; (void)n_in; (void)out_size; (void)ws_size;
  const float* Xmu  = (const float*)d_in[0];
  const float* Yeta = (const float*)d_in[1];
  const float* Ymu  = (const float*)d_in[2];
  const float* Z    = (const float*)d_in[3];
  float* out = (float*)d_out;

  char* w = (char*)d_ws;
  float*  U4      = (float*)(w);                      // 128 KB
  float*  UN      = (float*)(w + (128 << 10));        // 32 KB
  float*  M4      = (float*)(w + (160 << 10));        // 128 KB
  float*  Y4      = (float*)(w + (288 << 10));        // 128 KB
  double* x       = (double*)(w + (416 << 10));       // 128 KB
  double* rb[2]   = { (double*)(w + (544 << 10)), (double*)(w + (672 << 10)) };
  double* pb[2]   = { (double*)(w + (800 << 10)), (double*)(w + (928 << 10)) };
  double* qb[2]   = { (double*)(w + (1056 << 10)), (double*)(w + (1184 << 10)) };
  double* part[2] = { (double*)(w + (1312 << 10)), (double*)(w + (1325 << 10)) }; // 12.3 KB each
  double* rho[2]  = { (double*)(w + (1338 << 10)), (double*)(w + (1338 << 10) + 64) };
  double* rrsetup = (double*)(w + (1339 << 10));      // 512 B
  double* mmdpart = (double*)(w + (1340 << 10));      // 6 KB

  hipLaunchKernelGGL(k_setup, dim3(N2 / TPB), dim3(TPB), 0, stream,
                     Xmu, Yeta, Ymu, Z, U4, UN, M4, Y4,
                     x, rb[1], pb[1], qb[1], rrsetup);
  hipLaunchKernelGGL(k_mmd, dim3(256), dim3(MTPB), 0, stream, M4, Y4, mmdpart);
  for (int t = 0; t < T_ITERS; ++t) {
    int cur = t & 1, prv = cur ^ 1;
    hipLaunchKernelGGL(k_cg, dim3(NBLK), dim3(TPB), 0, stream,
                       U4, UN, rb[prv], pb[prv], qb[prv],
                       rb[cur], pb[cur], qb[cur], x,
                       part[prv], part[cur], rho[prv], rho[cur], rrsetup, t);
  }
  int last = (T_ITERS - 1) & 1;
  hipLaunchKernelGGL(k_final, dim3(1), dim3(TPB), 0, stream,
                     Z, x, pb[last], part[last], rho[last], mmdpart, out);
}